// Round 7
// baseline (338.886 us; speedup 1.0000x reference)
//
#include <hip/hip_runtime.h>
#include <hip/hip_bf16.h>

#define NBATCH 256
#define NT 512
#define ND 256
#define NROWS (NBATCH * NT)
#define CHUNK 64
#define NCHUNK (NROWS / CHUNK)    // 2048 blocks, 8 chunks per batch

typedef __attribute__((ext_vector_type(8))) short short8;
typedef __attribute__((ext_vector_type(4))) float floatx4;

__device__ __forceinline__ unsigned short f2bf(float x) {
    // round-to-nearest-even fp32 -> bf16
    unsigned int u = __float_as_uint(x);
    u += 0x7FFFu + ((u >> 16) & 1u);
    return (unsigned short)(u >> 16);
}

__device__ __forceinline__ short8 cvt8(float4 lo, float4 hi) {
    short8 v;
    v[0] = (short)f2bf(lo.x); v[1] = (short)f2bf(lo.y);
    v[2] = (short)f2bf(lo.z); v[3] = (short)f2bf(lo.w);
    v[4] = (short)f2bf(hi.x); v[5] = (short)f2bf(hi.y);
    v[6] = (short)f2bf(hi.z); v[7] = (short)f2bf(hi.w);
    return v;
}

// prep: W fp32 [D,D] (e,d) -> bf16 chunks in MFMA-FRAG ORDER.
// chunk g (16B = 8 bf16) = nb*512 + s*64 + q*16 + m
//   <-> W[e = nb*16 + m][k = q*8 + s*32 .. +8]
__global__ void __launch_bounds__(256) prep_kernel(
    const float* __restrict__ W, unsigned short* __restrict__ wf)
{
    int g  = blockIdx.x * 256 + threadIdx.x;   // 8192 chunks
    int m  = g & 15, q = (g >> 4) & 3, s = (g >> 6) & 7, nb = g >> 9;
    const float* src = W + (nb * 16 + m) * ND + q * 8 + s * 32;
    float4 f0 = *(const float4*)src;
    float4 f1 = *(const float4*)(src + 4);
    *(short8*)(wf + (long)g * 8) = cvt8(f0, f1);
}

// FUSED v5: identical structure to v4 (1 tile/wave, W direct from global,
// SW-pipelined prefetch, no main-loop barriers) with ONE change:
// __launch_bounds__(256, 8). v4 measured VGPR=52 (fits the 64-reg budget of
// 8 waves/SIMD), yet requested only 4 -> Occupancy 37%, ~156K of 211K
// CU-cycles in vmcnt-wait with ~3 waves/SIMD to hide them. At 8 blocks/CU
// (32 waves/CU) ALL 2048 blocks are co-resident; 8 waves/SIMD interleave
// to fill the latency holes of the W/A streams.
__global__ void __launch_bounds__(256, 8) fused_kernel(
    const float* __restrict__ ip,             // [B*T, D] fp32
    const unsigned short* __restrict__ wf,    // frag-ordered W bf16
    const float* __restrict__ bias,           // [D] fp32
    const float* __restrict__ ctx,            // [D] fp32
    float* __restrict__ gpart,                // [NCHUNK, 256] fp32 partials
    float2* __restrict__ ml)                  // [NCHUNK] (max, sumexp)
{
    __shared__ float score_s[CHUNK];
    __shared__ float w_s[CHUNK];
    __shared__ __align__(16) float partial[4][ND];

    const int tid  = threadIdx.x;
    const int lane = tid & 63;
    const int wv   = tid >> 6;        // wave 0..3
    const int m    = lane & 15;       // A row / W e-col within tile
    const int q    = lane >> 4;       // k-quad
    const long row0 = (long)blockIdx.x * CHUNK + wv * 16;

    // ---- A fragments: ONE tile (16 rows), loads batched 8-deep ----
    short8 a[8];
    {
        const float* ar = ip + (row0 + m) * ND + q * 8;
        float4 raw[8];
#pragma unroll
        for (int g = 0; g < 2; ++g) {
#pragma unroll
            for (int i = 0; i < 4; ++i) {
                raw[2 * i]     = *(const float4*)(ar + (4 * g + i) * 32);
                raw[2 * i + 1] = *(const float4*)(ar + (4 * g + i) * 32 + 4);
            }
#pragma unroll
            for (int i = 0; i < 4; ++i)
                a[4 * g + i] = cvt8(raw[2 * i], raw[2 * i + 1]);
        }
    }

    float sc[4] = {0.f, 0.f, 0.f, 0.f};
    const short8* wch = (const short8*)wf;

    // ---- scores: nb loop, W prefetched one 4-chunk group ahead ----
    short8 w0[4], w1[4];
#pragma unroll
    for (int s = 0; s < 4; ++s) w0[s] = (wch + lane)[s * 64];

#pragma unroll 1
    for (int nb = 0; nb < 16; ++nb) {
        const short8* wbase = wch + nb * 512 + lane;
#pragma unroll
        for (int s = 0; s < 4; ++s) w1[s] = wbase[(s + 4) * 64];
        const int e = nb * 16 + m;
        const float be = bias[e];         // issued early, hides under MFMAs
        const float ce = ctx[e];

        floatx4 acc = {0.f, 0.f, 0.f, 0.f};
#pragma unroll
        for (int s = 0; s < 4; ++s)
            acc = __builtin_amdgcn_mfma_f32_16x16x32_bf16(a[s], w0[s], acc, 0, 0, 0);
        if (nb < 15) {                    // prefetch next group under 2nd MFMA run
            const short8* wnext = wch + (nb + 1) * 512 + lane;
#pragma unroll
            for (int s = 0; s < 4; ++s) w0[s] = wnext[s * 64];
        }
#pragma unroll
        for (int s = 0; s < 4; ++s)
            acc = __builtin_amdgcn_mfma_f32_16x16x32_bf16(a[s + 4], w1[s], acc, 0, 0, 0);

        const float ce2 = ce + ce;
#pragma unroll
        for (int r = 0; r < 4; ++r) {     // acc[r] = D[row=q*4+r][col=m]
            float x = acc[r] + be;
            // tanh(x)*ce = ce - ce2 * rcp(exp(2x)+1)
            float t = __builtin_amdgcn_rcpf(__expf(x + x) + 1.f);
            sc[r] = __builtin_fmaf(-ce2, t, sc[r] + ce);
        }
    }

    // sum over 16 e-cols spread across lanes sharing a quad (xor lane bits 0..3)
#pragma unroll
    for (int off = 8; off >= 1; off >>= 1)
#pragma unroll
        for (int r = 0; r < 4; ++r) sc[r] += __shfl_xor(sc[r], off, 64);
    if (m == 0)
#pragma unroll
        for (int r = 0; r < 4; ++r) score_s[wv * 16 + q * 4 + r] = sc[r];
    __syncthreads();

    // ---- chunk softmax over 64 scores (each wave redundantly) ----
    float s0 = score_s[lane];
    float mx = s0;
#pragma unroll
    for (int off = 32; off >= 1; off >>= 1) mx = fmaxf(mx, __shfl_xor(mx, off, 64));
    float ev = __expf(s0 - mx);
    float ls = ev;
#pragma unroll
    for (int off = 32; off >= 1; off >>= 1) ls += __shfl_xor(ls, off, 64);
    if (wv == 0) w_s[lane] = ev;                  // UNNORMALIZED e^{s-mx}
    if (tid == 0) ml[blockIdx.x] = make_float2(mx, ls);
    __syncthreads();

    // ---- phase 2: weighted sum, wave wv -> chunk rows [wv*16, wv*16+16) ----
    // lane = float4 col; 1KB contiguous per row across the wave (L2/L3-hot)
    const int prow = wv * 16;
    const float4* base = (const float4*)(ip + ((long)blockIdx.x * CHUNK + prow) * ND) + lane;
    float4 acc4 = {0.f, 0.f, 0.f, 0.f};
#pragma unroll
    for (int r = 0; r < 16; ++r) {
        const float wt = w_s[prow + r];   // wave-uniform LDS broadcast
        const float4 v = base[(long)r * 64];
        acc4.x += wt * v.x; acc4.y += wt * v.y;
        acc4.z += wt * v.z; acc4.w += wt * v.w;
    }
    ((float4*)&partial[wv][0])[lane] = acc4;
    __syncthreads();
    {   // 256 threads == ND columns
        float r = partial[0][tid] + partial[1][tid]
                + partial[2][tid] + partial[3][tid];
        gpart[(long)blockIdx.x * ND + tid] = r;
    }
}

// combine: merge the 8 chunk partials of each batch with softmax rescale.
// out[b,d] = sum_c e^{m_c-M} acc_c[d] / sum_c e^{m_c-M} l_c
__global__ void __launch_bounds__(256) combine_kernel(
    const float4* __restrict__ gpart4,   // [NCHUNK, 64] float4
    const float2* __restrict__ ml,       // [NCHUNK]
    float4* __restrict__ out4)           // [B, 64] float4
{
    const int b = blockIdx.x * 4 + (threadIdx.x >> 6);   // wave -> batch
    const int c = threadIdx.x & 63;
    const float2* mlb = ml + b * 8;
    float mk[8], lk[8];
#pragma unroll
    for (int k = 0; k < 8; ++k) { float2 p = mlb[k]; mk[k] = p.x; lk[k] = p.y; }
    float M = mk[0];
#pragma unroll
    for (int k = 1; k < 8; ++k) M = fmaxf(M, mk[k]);
    float L = 0.f, f[8];
#pragma unroll
    for (int k = 0; k < 8; ++k) { f[k] = __expf(mk[k] - M); L += f[k] * lk[k]; }
    float4 acc = {0.f, 0.f, 0.f, 0.f};
#pragma unroll
    for (int k = 0; k < 8; ++k) {
        float4 v = gpart4[(long)(b * 8 + k) * 64 + c];
        acc.x += f[k] * v.x; acc.y += f[k] * v.y;
        acc.z += f[k] * v.z; acc.w += f[k] * v.w;
    }
    float inv = 1.f / L;
    acc.x *= inv; acc.y *= inv; acc.z *= inv; acc.w *= inv;
    out4[(long)b * 64 + c] = acc;
}

extern "C" void kernel_launch(void* const* d_in, const int* in_sizes, int n_in,
                              void* d_out, int out_size, void* d_ws, size_t ws_size,
                              hipStream_t stream) {
    const float* ip   = (const float*)d_in[0];
    const float* W    = (const float*)d_in[1];
    const float* bias = (const float*)d_in[2];
    const float* ctx  = (const float*)d_in[3];

    unsigned short* wf = (unsigned short*)d_ws;                              // 128 KB
    float* gpart = (float*)((char*)d_ws + ND * ND * sizeof(unsigned short)); // 2 MB
    float2* ml   = (float2*)((char*)gpart + (long)NCHUNK * ND * sizeof(float)); // 16 KB

    prep_kernel<<<32, 256, 0, stream>>>(W, wf);
    fused_kernel<<<NCHUNK, 256, 0, stream>>>(ip, wf, bias, ctx, gpart, ml);
    combine_kernel<<<NBATCH / 4, 256, 0, stream>>>((const float4*)gpart, ml, (float4*)d_out);
}

// Round 8
// 223.844 us; speedup vs baseline: 1.5139x; 1.5139x over previous
//
#include <hip/hip_runtime.h>
#include <hip/hip_bf16.h>

#define NBATCH 256
#define NT 512
#define ND 256
#define NROWS (NBATCH * NT)
#define CHUNK 64
#define NCHUNK (NROWS / CHUNK)    // 2048 blocks, 8 chunks per batch

typedef __attribute__((ext_vector_type(8))) short short8;
typedef __attribute__((ext_vector_type(4))) float floatx4;

__device__ __forceinline__ unsigned short f2bf(float x) {
    // round-to-nearest-even fp32 -> bf16
    unsigned int u = __float_as_uint(x);
    u += 0x7FFFu + ((u >> 16) & 1u);
    return (unsigned short)(u >> 16);
}

__device__ __forceinline__ short8 cvt8(float4 lo, float4 hi) {
    short8 v;
    v[0] = (short)f2bf(lo.x); v[1] = (short)f2bf(lo.y);
    v[2] = (short)f2bf(lo.z); v[3] = (short)f2bf(lo.w);
    v[4] = (short)f2bf(hi.x); v[5] = (short)f2bf(hi.y);
    v[6] = (short)f2bf(hi.z); v[7] = (short)f2bf(hi.w);
    return v;
}

// prep: W fp32 [D,D] (e,d) -> bf16 chunks in MFMA-FRAG ORDER.
// chunk g (16B = 8 bf16) = nb*512 + s*64 + q*16 + m
//   <-> W[e = nb*16 + m][k = q*8 + s*32 .. +8]
__global__ void __launch_bounds__(256) prep_kernel(
    const float* __restrict__ W, unsigned short* __restrict__ wf)
{
    int g  = blockIdx.x * 256 + threadIdx.x;   // 8192 chunks
    int m  = g & 15, q = (g >> 4) & 3, s = (g >> 6) & 7, nb = g >> 9;
    const float* src = W + (nb * 16 + m) * ND + q * 8 + s * 32;
    float4 f0 = *(const float4*)src;
    float4 f1 = *(const float4*)(src + 4);
    *(short8*)(wf + (long)g * 8) = cvt8(f0, f1);
}

// FUSED v6: T14 async-STAGE double-buffered W pipeline, no waves-per-EU hint.
// Block = 64 rows (1 chunk), 256 thr, 4 waves x 16 rows.
// W staged e-tile by e-tile (16 stages x 8KB) through a 2x8KB LDS dbuf:
//   per stage: ISSUE 2 global loads for stage t+1 (regs, no wait)
//              -> compute stage t from LDS (8 ds_read_b128 + 8 MFMA + tanh)
//              -> ds_write stage t+1 (vmcnt wait lands AFTER compute)
//              -> one barrier.
// Stage-load latency hides under compute (unlike r2's load->barrier->compute,
// which hid nothing). No __launch_bounds__ waves hint: r2-r7 showed the hint
// pins residency (~4 waves/EU at (,4); spill at (,8)); with ~85 VGPR and
// 20.5KB LDS the HW can host 5-7 blocks/CU and residency floats up.
__global__ void __launch_bounds__(256) fused_kernel(
    const float* __restrict__ ip,             // [B*T, D] fp32
    const unsigned short* __restrict__ wf,    // frag-ordered W bf16
    const float* __restrict__ bias,           // [D] fp32
    const float* __restrict__ ctx,            // [D] fp32
    float* __restrict__ gpart,                // [NCHUNK, 256] fp32 partials
    float2* __restrict__ ml)                  // [NCHUNK] (max, sumexp)
{
    __shared__ __align__(16) short8 wbuf[2][512];    // 2 x 8KB W stage dbuf
    __shared__ float score_s[CHUNK];
    __shared__ float w_s[CHUNK];
    __shared__ __align__(16) float partial[4][ND];

    const int tid  = threadIdx.x;
    const int lane = tid & 63;
    const int wv   = tid >> 6;        // wave 0..3
    const int m    = lane & 15;       // A row / W e-col within tile
    const int q    = lane >> 4;       // k-quad
    const long row0 = (long)blockIdx.x * CHUNK + wv * 16;

    const short8* wch = (const short8*)wf;

    // ---- stage-0 W loads issued first (longest latency cover) ----
    short8 st0 = wch[tid];
    short8 st1 = wch[256 + tid];

    // ---- A fragments: ONE tile (16 rows), loads batched 8-deep ----
    short8 a[8];
    {
        const float* ar = ip + (row0 + m) * ND + q * 8;
        float4 raw[8];
#pragma unroll
        for (int g = 0; g < 2; ++g) {
#pragma unroll
            for (int i = 0; i < 4; ++i) {
                raw[2 * i]     = *(const float4*)(ar + (4 * g + i) * 32);
                raw[2 * i + 1] = *(const float4*)(ar + (4 * g + i) * 32 + 4);
            }
#pragma unroll
            for (int i = 0; i < 4; ++i)
                a[4 * g + i] = cvt8(raw[2 * i], raw[2 * i + 1]);
        }
    }

    // stage-0 into buf 0
    wbuf[0][tid]       = st0;
    wbuf[0][256 + tid] = st1;
    __syncthreads();

    float sc[4] = {0.f, 0.f, 0.f, 0.f};
    int cur = 0;

#pragma unroll 1
    for (int nb = 0; nb < 16; ++nb) {
        // ---- issue stage nb+1 global loads (consumed after compute) ----
        short8 n0, n1;
        if (nb < 15) {
            n0 = wch[(nb + 1) * 512 + tid];
            n1 = wch[(nb + 1) * 512 + 256 + tid];
        }

        // ---- compute e-tile nb from resident buffer ----
        const short8* wp = &wbuf[cur][0] + lane;   // lane-linear ds_read_b128
        short8 w[4];
#pragma unroll
        for (int s = 0; s < 4; ++s) w[s] = wp[s * 64];
        floatx4 acc = {0.f, 0.f, 0.f, 0.f};
#pragma unroll
        for (int s = 0; s < 4; ++s)
            acc = __builtin_amdgcn_mfma_f32_16x16x32_bf16(a[s], w[s], acc, 0, 0, 0);
#pragma unroll
        for (int s = 0; s < 4; ++s) w[s] = wp[(s + 4) * 64];
#pragma unroll
        for (int s = 0; s < 4; ++s)
            acc = __builtin_amdgcn_mfma_f32_16x16x32_bf16(a[s + 4], w[s], acc, 0, 0, 0);

        const int e = nb * 16 + m;
        const float be  = bias[e];        // 1KB tables, L1-hot
        const float ce  = ctx[e];
        const float ce2 = ce + ce;
#pragma unroll
        for (int r = 0; r < 4; ++r) {     // acc[r] = D[row=q*4+r][col=m]
            float x = acc[r] + be;
            // tanh(x)*ce = ce - ce2 * rcp(exp(2x)+1)
            float t = __builtin_amdgcn_rcpf(__expf(x + x) + 1.f);
            sc[r] = __builtin_fmaf(-ce2, t, sc[r] + ce);
        }

        // ---- write stage nb+1 (vmcnt wait for n0/n1 lands here) ----
        if (nb < 15) {
            wbuf[cur ^ 1][tid]       = n0;
            wbuf[cur ^ 1][256 + tid] = n1;
        }
        __syncthreads();
        cur ^= 1;
    }

    // sum over 16 e-cols spread across lanes sharing a quad (xor lane bits 0..3)
#pragma unroll
    for (int off = 8; off >= 1; off >>= 1)
#pragma unroll
        for (int r = 0; r < 4; ++r) sc[r] += __shfl_xor(sc[r], off, 64);
    if (m == 0)
#pragma unroll
        for (int r = 0; r < 4; ++r) score_s[wv * 16 + q * 4 + r] = sc[r];
    __syncthreads();

    // ---- chunk softmax over 64 scores (each wave redundantly) ----
    float s0 = score_s[lane];
    float mx = s0;
#pragma unroll
    for (int off = 32; off >= 1; off >>= 1) mx = fmaxf(mx, __shfl_xor(mx, off, 64));
    float ev = __expf(s0 - mx);
    float ls = ev;
#pragma unroll
    for (int off = 32; off >= 1; off >>= 1) ls += __shfl_xor(ls, off, 64);
    if (wv == 0) w_s[lane] = ev;                  // UNNORMALIZED e^{s-mx}
    if (tid == 0) ml[blockIdx.x] = make_float2(mx, ls);
    __syncthreads();

    // ---- phase 2: weighted sum, wave wv -> chunk rows [wv*16, wv*16+16) ----
    // lane = float4 col; 1KB contiguous per row across the wave (L2/L3-hot)
    const int prow = wv * 16;
    const float4* base = (const float4*)(ip + ((long)blockIdx.x * CHUNK + prow) * ND) + lane;
    float4 acc4 = {0.f, 0.f, 0.f, 0.f};
#pragma unroll
    for (int r = 0; r < 16; ++r) {
        const float wt = w_s[prow + r];   // wave-uniform LDS broadcast
        const float4 v = base[(long)r * 64];
        acc4.x += wt * v.x; acc4.y += wt * v.y;
        acc4.z += wt * v.z; acc4.w += wt * v.w;
    }
    ((float4*)&partial[wv][0])[lane] = acc4;
    __syncthreads();
    {   // 256 threads == ND columns
        float r = partial[0][tid] + partial[1][tid]
                + partial[2][tid] + partial[3][tid];
        gpart[(long)blockIdx.x * ND + tid] = r;
    }
}

// combine: merge the 8 chunk partials of each batch with softmax rescale.
// out[b,d] = sum_c e^{m_c-M} acc_c[d] / sum_c e^{m_c-M} l_c
__global__ void __launch_bounds__(256) combine_kernel(
    const float4* __restrict__ gpart4,   // [NCHUNK, 64] float4
    const float2* __restrict__ ml,       // [NCHUNK]
    float4* __restrict__ out4)           // [B, 64] float4
{
    const int b = blockIdx.x * 4 + (threadIdx.x >> 6);   // wave -> batch
    const int c = threadIdx.x & 63;
    const float2* mlb = ml + b * 8;
    float mk[8], lk[8];
#pragma unroll
    for (int k = 0; k < 8; ++k) { float2 p = mlb[k]; mk[k] = p.x; lk[k] = p.y; }
    float M = mk[0];
#pragma unroll
    for (int k = 1; k < 8; ++k) M = fmaxf(M, mk[k]);
    float L = 0.f, f[8];
#pragma unroll
    for (int k = 0; k < 8; ++k) { f[k] = __expf(mk[k] - M); L += f[k] * lk[k]; }
    float4 acc = {0.f, 0.f, 0.f, 0.f};
#pragma unroll
    for (int k = 0; k < 8; ++k) {
        float4 v = gpart4[(long)(b * 8 + k) * 64 + c];
        acc.x += f[k] * v.x; acc.y += f[k] * v.y;
        acc.z += f[k] * v.z; acc.w += f[k] * v.w;
    }
    float inv = 1.f / L;
    acc.x *= inv; acc.y *= inv; acc.z *= inv; acc.w *= inv;
    out4[(long)b * 64 + c] = acc;
}

extern "C" void kernel_launch(void* const* d_in, const int* in_sizes, int n_in,
                              void* d_out, int out_size, void* d_ws, size_t ws_size,
                              hipStream_t stream) {
    const float* ip   = (const float*)d_in[0];
    const float* W    = (const float*)d_in[1];
    const float* bias = (const float*)d_in[2];
    const float* ctx  = (const float*)d_in[3];

    unsigned short* wf = (unsigned short*)d_ws;                              // 128 KB
    float* gpart = (float*)((char*)d_ws + ND * ND * sizeof(unsigned short)); // 2 MB
    float2* ml   = (float2*)((char*)gpart + (long)NCHUNK * ND * sizeof(float)); // 16 KB

    prep_kernel<<<32, 256, 0, stream>>>(W, wf);
    fused_kernel<<<NCHUNK, 256, 0, stream>>>(ip, wf, bias, ctx, gpart, ml);
    combine_kernel<<<NBATCH / 4, 256, 0, stream>>>((const float4*)gpart, ml, (float4*)d_out);
}